// Round 5
// baseline (401.358 us; speedup 1.0000x reference)
//
#include <hip/hip_runtime.h>
#include <hip/hip_bf16.h>

// Problem constants
#define EDIM 1024
#define TDIM 2048
#define MTOT 32768   // B*T = 16*2048

typedef __attribute__((ext_vector_type(8))) short short8;
typedef __attribute__((ext_vector_type(8))) unsigned short ushort8;
typedef __attribute__((ext_vector_type(4))) float f32x4;

__device__ __forceinline__ ushort f2bf(float f) {
  unsigned u = __float_as_uint(f);
  u += 0x7fff + ((u >> 16) & 1);   // RNE
  return (ushort)(u >> 16);
}
__device__ __forceinline__ float bf2f(ushort h) {
  return __uint_as_float(((unsigned)h) << 16);
}

// ---------------------------------------------------------------------------
// K0: Psum[c][e] = sum_h pos_w[h,e,c]  (f32 inputs). 12x256 = 3072 threads.
// ---------------------------------------------------------------------------
__global__ __launch_bounds__(256) void prep_kernel(
    const float* __restrict__ pos_w, float* __restrict__ Psum) {
  int idx = blockIdx.x * 256 + threadIdx.x;       // 0..3071
  int c = idx >> 10, e = idx & 1023;
  float s = 0.f;
#pragma unroll
  for (int h = 0; h < 8; ++h) s += pos_w[h * (EDIM * 3) + e * 3 + c];
  Psum[idx] = s;                                  // layout Psum[c*1024 + e]
}

// ---------------------------------------------------------------------------
// K1: mid[m,e] = (1/24) * sum_c s_c * win_c[e];  s_c = <win_c, Psum[c]>
//     win_c = embed_table[tokens[m-2+c]] (f32), zeros when t-2+c < 0.
// One block per token m; 256 threads x 4 elems. Writes bf16 mid into ws.
// ---------------------------------------------------------------------------
__global__ __launch_bounds__(256) void mid_kernel(
    const int* __restrict__ tokens, const float* __restrict__ embed,
    const float* __restrict__ Psum, ushort* __restrict__ mid) {
  int m = blockIdx.x;
  int t = m & (TDIM - 1);
  int tid = threadIdx.x;
  int e4 = tid << 2;

  float4 r0 = make_float4(0.f, 0.f, 0.f, 0.f), r1 = r0, r2;
  float p0 = 0.f, p1 = 0.f, p2;

  if (t >= 2) {
    r0 = *(const float4*)&embed[(size_t)tokens[m - 2] * EDIM + e4];
    float4 ps = *(const float4*)&Psum[0 * EDIM + e4];
    p0 = r0.x * ps.x + r0.y * ps.y + r0.z * ps.z + r0.w * ps.w;
  }
  if (t >= 1) {
    r1 = *(const float4*)&embed[(size_t)tokens[m - 1] * EDIM + e4];
    float4 ps = *(const float4*)&Psum[1 * EDIM + e4];
    p1 = r1.x * ps.x + r1.y * ps.y + r1.z * ps.z + r1.w * ps.w;
  }
  {
    r2 = *(const float4*)&embed[(size_t)tokens[m] * EDIM + e4];
    float4 ps = *(const float4*)&Psum[2 * EDIM + e4];
    p2 = r2.x * ps.x + r2.y * ps.y + r2.z * ps.z + r2.w * ps.w;
  }

#pragma unroll
  for (int off = 32; off; off >>= 1) {
    p0 += __shfl_xor(p0, off);
    p1 += __shfl_xor(p1, off);
    p2 += __shfl_xor(p2, off);
  }
  __shared__ float red[4][3];
  int wv = tid >> 6, ln = tid & 63;
  if (ln == 0) { red[wv][0] = p0; red[wv][1] = p1; red[wv][2] = p2; }
  __syncthreads();
  float s0 = (red[0][0] + red[1][0]) + (red[2][0] + red[3][0]);
  float s1 = (red[0][1] + red[1][1]) + (red[2][1] + red[3][1]);
  float s2 = (red[0][2] + red[1][2]) + (red[2][2] + red[3][2]);

  const float inv = 1.0f / 24.0f;
  ushort4 o;
  o.x = f2bf((s0 * r0.x + s1 * r1.x + s2 * r2.x) * inv);
  o.y = f2bf((s0 * r0.y + s1 * r1.y + s2 * r2.y) * inv);
  o.z = f2bf((s0 * r0.z + s1 * r1.z + s2 * r2.z) * inv);
  o.w = f2bf((s0 * r0.w + s1 * r1.w + s2 * r2.w) * inv);
  *(ushort4*)&mid[(size_t)m * EDIM + e4] = o;
}

// ---------------------------------------------------------------------------
// K2: y[m,n] = sum_k mid[m,k]*W[n,k] + bias[n]   (gemm_bt, bf16 MFMA)
// A = mid (bf16, in ws). W = ffn_w f32, converted to bf16 inline during LDS
// staging. bias f32. Writes *** f32 y *** into d_out (output dtype is f32!).
// 128x128 tile, BK=32, 4 waves each 64x64 (4x4 of 16x16x32).
// A-frag: A[m=lane&15][k=(lane>>4)*8+j]; C/D: col=lane&15, row=(lane>>4)*4+reg
// [guide 3, measured m89/m91/m97].
// ---------------------------------------------------------------------------
__global__ __launch_bounds__(256) void gemm_kernel(
    const ushort* __restrict__ A, const float* __restrict__ W,
    const float* __restrict__ bias, float* __restrict__ out) {
  __shared__ ushort As[128 * 32];
  __shared__ ushort Bs[128 * 32];
  int tid = threadIdx.x;
  int wave = tid >> 6, lane = tid & 63;
  int tileM = blockIdx.y << 7;   // grid.y = 256
  int tileN = blockIdx.x << 7;   // grid.x = 8
  int wm = (wave >> 1) << 6;
  int wn = (wave & 1) << 6;

  f32x4 acc[4][4];
#pragma unroll
  for (int i = 0; i < 4; ++i)
#pragma unroll
    for (int j = 0; j < 4; ++j) acc[i][j] = (f32x4){0.f, 0.f, 0.f, 0.f};

  int srow = tid >> 2;           // 0..63
  int scol = (tid & 3) << 3;     // 0,8,16,24
  const ushort* Ap = A + (size_t)(tileM + srow) * EDIM + scol;
  const float*  Wp = W + (size_t)(tileN + srow) * EDIM + scol;
  int arow = lane & 15;
  int kq = (lane >> 4) << 3;

  for (int k0 = 0; k0 < EDIM; k0 += 32) {
    *(int4*)&As[srow * 32 + scol]        = *(const int4*)(Ap + k0);
    *(int4*)&As[(srow + 64) * 32 + scol] = *(const int4*)(Ap + (size_t)64 * EDIM + k0);
    {
      float4 b0 = *(const float4*)(Wp + k0);
      float4 b1 = *(const float4*)(Wp + k0 + 4);
      ushort8 u;
      u[0] = f2bf(b0.x); u[1] = f2bf(b0.y); u[2] = f2bf(b0.z); u[3] = f2bf(b0.w);
      u[4] = f2bf(b1.x); u[5] = f2bf(b1.y); u[6] = f2bf(b1.z); u[7] = f2bf(b1.w);
      *(ushort8*)&Bs[srow * 32 + scol] = u;
      float4 c0 = *(const float4*)(Wp + (size_t)64 * EDIM + k0);
      float4 c1 = *(const float4*)(Wp + (size_t)64 * EDIM + k0 + 4);
      ushort8 v;
      v[0] = f2bf(c0.x); v[1] = f2bf(c0.y); v[2] = f2bf(c0.z); v[3] = f2bf(c0.w);
      v[4] = f2bf(c1.x); v[5] = f2bf(c1.y); v[6] = f2bf(c1.z); v[7] = f2bf(c1.w);
      *(ushort8*)&Bs[(srow + 64) * 32 + scol] = v;
    }
    __syncthreads();

    short8 af[4], bfr[4];
#pragma unroll
    for (int i = 0; i < 4; ++i) {
      af[i]  = *(const short8*)&As[(wm + i * 16 + arow) * 32 + kq];
      bfr[i] = *(const short8*)&Bs[(wn + i * 16 + arow) * 32 + kq];
    }
#pragma unroll
    for (int i = 0; i < 4; ++i)
#pragma unroll
      for (int j = 0; j < 4; ++j)
        acc[i][j] = __builtin_amdgcn_mfma_f32_16x16x32_bf16(af[i], bfr[j], acc[i][j], 0, 0, 0);
    __syncthreads();
  }

  int col0 = lane & 15, rq = (lane >> 4) << 2;
#pragma unroll
  for (int j = 0; j < 4; ++j) {
    int col = tileN + wn + j * 16 + col0;
    float bv = bias[col];
#pragma unroll
    for (int i = 0; i < 4; ++i) {
      int row = tileM + wm + i * 16 + rq;
#pragma unroll
      for (int r = 0; r < 4; ++r)
        out[(size_t)(row + r) * EDIM + col] = acc[i][j][r] + bv;   // f32 store
    }
  }
}

// ---------------------------------------------------------------------------
// K3: LayerNorm + swish, IN-PLACE f32 on d_out. Block = one row of 1024.
// Per-row in-place: block m reads and writes only bytes [4096m, 4096m+4096).
// ---------------------------------------------------------------------------
__global__ __launch_bounds__(256) void ln_kernel(
    float* __restrict__ y, const float* __restrict__ g,
    const float* __restrict__ bta) {
  int m = blockIdx.x, tid = threadIdx.x;
  int e4 = tid << 2;
  float4 v = *(const float4*)&y[(size_t)m * EDIM + e4];
  float s = (v.x + v.y) + (v.z + v.w);
  float q = (v.x * v.x + v.y * v.y) + (v.z * v.z + v.w * v.w);
#pragma unroll
  for (int off = 32; off; off >>= 1) {
    s += __shfl_xor(s, off);
    q += __shfl_xor(q, off);
  }
  __shared__ float red[4][2];
  int wv = tid >> 6, ln = tid & 63;
  if (ln == 0) { red[wv][0] = s; red[wv][1] = q; }
  __syncthreads();
  float S = (red[0][0] + red[1][0]) + (red[2][0] + red[3][0]);
  float Q = (red[0][1] + red[1][1]) + (red[2][1] + red[3][1]);
  float mu = S * (1.0f / EDIM);
  float var = Q * (1.0f / EDIM) - mu * mu;
  float rs = rsqrtf(var + 1e-5f);
  float4 gg = *(const float4*)&g[e4];
  float4 bb = *(const float4*)&bta[e4];
  float x0 = (v.x - mu) * rs * gg.x + bb.x;
  float x1 = (v.y - mu) * rs * gg.y + bb.y;
  float x2 = (v.z - mu) * rs * gg.z + bb.z;
  float x3 = (v.w - mu) * rs * gg.w + bb.w;
  float4 o;
  o.x = x0 / (1.f + expf(-x0));
  o.y = x1 / (1.f + expf(-x1));
  o.z = x2 / (1.f + expf(-x2));
  o.w = x3 / (1.f + expf(-x3));
  *(float4*)&y[(size_t)m * EDIM + e4] = o;
}

// ---------------------------------------------------------------------------
// Buffer plan (ws usage = 64 MiB + 12 KiB, proven in-bounds in earlier rounds):
//   ws[0 : 64 MiB)                 mid   (bf16; mid_kernel -> gemm)
//   ws[64 MiB : 64 MiB + 12 KiB)   Psum  (prep -> mid)
//   d_out (f32, 128 MB)            y     (gemm, f32) -> final (ln in-place)
// Inputs are f32 (round-4 NaN proved bf16-reading is wrong); OUTPUT IS F32
// per harness doc (reference output dtype = float32).
// ---------------------------------------------------------------------------
extern "C" void kernel_launch(void* const* d_in, const int* in_sizes, int n_in,
                              void* d_out, int out_size, void* d_ws, size_t ws_size,
                              hipStream_t stream) {
  const int*   tokens = (const int*)d_in[0];
  const float* embed  = (const float*)d_in[1];
  const float* pos_w  = (const float*)d_in[2];
  const float* ffn_w  = (const float*)d_in[3];
  const float* ffn_b  = (const float*)d_in[4];
  const float* ln_g   = (const float*)d_in[5];
  const float* ln_b   = (const float*)d_in[6];

  char* ws = (char*)d_ws;
  float*  outp = (float*)d_out;                              // f32 output!
  ushort* midw = (ushort*)ws;                                // 64 MiB bf16
  float*  Psum = (float*)(ws + (size_t)64 * 1024 * 1024);    // 12 KiB

  prep_kernel<<<12, 256, 0, stream>>>(pos_w, Psum);
  mid_kernel<<<MTOT, 256, 0, stream>>>(tokens, embed, Psum, midw);
  dim3 g2(8, 256);
  gemm_kernel<<<g2, 256, 0, stream>>>(midw, ffn_w, ffn_b, outp);
  ln_kernel<<<MTOT, 256, 0, stream>>>(outp, ln_g, ln_b);
}